// Round 1
// baseline (1133.138 us; speedup 1.0000x reference)
//
#include <hip/hip_runtime.h>
#include <hip/hip_fp16.h>

typedef _Float16 f16;
typedef _Float16 f16x4 __attribute__((ext_vector_type(4)));
typedef _Float16 f16x8 __attribute__((ext_vector_type(8)));
typedef float    f32x4 __attribute__((ext_vector_type(4)));

#define NEG_INF (-__builtin_inff())

// ---------------------------------------------------------------- converts
__global__ __launch_bounds__(256) void cvt_f32_f16(const float* __restrict__ in,
                                                   f16* __restrict__ out, int n4) {
    int i = blockIdx.x * 256 + threadIdx.x;
    if (i >= n4) return;
    float4 v = ((const float4*)in)[i];
    f16x4 h = {(f16)v.x, (f16)v.y, (f16)v.z, (f16)v.w};
    ((f16x4*)out)[i] = h;
}

// ---------------------------------------------------------------- GEMM C = A * Bt^T
// A: [M,K] row-major f16. Bt: [N,K] row-major f16. C: [M,N] row-major (f16 or f32).
// block = 256 threads (4 waves, 2x2), tile 128x128, BK=32.
// MFMA 16x16x32_f16: A-frag A[m=lane&15][k=quad*8+j]; B-frag Bt[n=lane&15][k=quad*8+j];
// D: row=quad*4+reg, col=lane&15  (guide-verified layout, dtype-independent).
template <typename CT>
__global__ __launch_bounds__(256) void gemm_bt(const f16* __restrict__ A,
                                               const f16* __restrict__ Bt,
                                               CT* __restrict__ C, int M, int N, int K) {
    __shared__ f16 As[128][40];   // +8 pad: rows land on distinct bank quads (2-way max)
    __shared__ f16 Bs[128][40];
    const int tid  = threadIdx.x;
    const int wave = tid >> 6, lane = tid & 63;
    const int quad = lane >> 4, m16 = lane & 15;
    const int waveM = (wave >> 1) * 64, waveN = (wave & 1) * 64;
    const int bm = blockIdx.y * 128, bn = blockIdx.x * 128;

    f32x4 acc[4][4];
#pragma unroll
    for (int i = 0; i < 4; ++i)
#pragma unroll
        for (int j = 0; j < 4; ++j)
#pragma unroll
            for (int e = 0; e < 4; ++e) acc[i][j][e] = 0.f;

    const int srow = tid >> 2;          // 0..63
    const int sc8  = (tid & 3) * 8;     // 0,8,16,24

    for (int k0 = 0; k0 < K; k0 += 32) {
        __syncthreads();
#pragma unroll
        for (int it = 0; it < 2; ++it) {
            int row = it * 64 + srow;
            *(f16x8*)&As[row][sc8] = *(const f16x8*)(A  + (size_t)(bm + row) * K + k0 + sc8);
            *(f16x8*)&Bs[row][sc8] = *(const f16x8*)(Bt + (size_t)(bn + row) * K + k0 + sc8);
        }
        __syncthreads();
        f16x8 af[4], bf[4];
#pragma unroll
        for (int t = 0; t < 4; ++t) af[t] = *(const f16x8*)&As[waveM + t * 16 + m16][quad * 8];
#pragma unroll
        for (int t = 0; t < 4; ++t) bf[t] = *(const f16x8*)&Bs[waveN + t * 16 + m16][quad * 8];
#pragma unroll
        for (int i = 0; i < 4; ++i)
#pragma unroll
            for (int j = 0; j < 4; ++j)
                acc[i][j] = __builtin_amdgcn_mfma_f32_16x16x32_f16(af[i], bf[j], acc[i][j], 0, 0, 0);
    }

#pragma unroll
    for (int i = 0; i < 4; ++i)
#pragma unroll
        for (int r = 0; r < 4; ++r) {
            int row = bm + waveM + i * 16 + quad * 4 + r;
#pragma unroll
            for (int j = 0; j < 4; ++j) {
                int col = bn + waveN + j * 16 + m16;
                C[(size_t)row * N + col] = (CT)acc[i][j][r];
            }
        }
}

// ---------------------------------------------------------------- RoPE + paged scatter
// qkv: [B*S, 6144] f16 (q 0:4096 | k 4096:5120 | v 5120:6144)
// qh:  [B,NH,S,HD] f16 (rope'd);  kc/vc: [NUM_BLOCKS*BLOCK=4096, NKV, HD] f16
__global__ __launch_bounds__(256) void rope_scatter(const f16* __restrict__ qkv,
                                                    const float* __restrict__ freqs,
                                                    const int* __restrict__ bt,
                                                    f16* __restrict__ qh,
                                                    f16* __restrict__ kc,
                                                    f16* __restrict__ vc) {
    int idx  = blockIdx.x * 256 + threadIdx.x;     // B*S*3072 pairs
    int row  = idx / 3072;
    int p    = idx - row * 3072;
    int b    = row >> 11, s = row & 2047;
    int head = p >> 6, i = p & 63;
    const f16* src = qkv + (size_t)row * 6144 + head * 128 + 2 * i;
    float v0 = (float)src[0], v1 = (float)src[1];
    if (head < 40) {  // rope on q and k
        float c  = freqs[s * 128 + 2 * i];
        float sn = freqs[s * 128 + 2 * i + 1];
        float r0 = v0 * c - v1 * sn;
        float r1 = v1 * c + v0 * sn;
        v0 = r0; v1 = r1;
    }
    if (head < 32) {
        f16* dst = qh + (((size_t)(b * 32 + head)) * 2048 + s) * 128 + 2 * i;
        dst[0] = (f16)v0; dst[1] = (f16)v1;
    } else {
        int kvh  = head - 32; if (kvh >= 8) kvh -= 8;
        int slot = bt[b * 128 + (s >> 4)] * 16 + (s & 15);
        f16* dst = (head < 40 ? kc : vc) + ((size_t)slot * 8 + kvh) * 128 + 2 * i;
        dst[0] = (f16)v0; dst[1] = (f16)v1;
    }
}

// ---------------------------------------------------------------- gather through block table
// kk:  [B,NKV,S,HD] f16;  vvt: [B,NKV,HD,S] f16 (transposed for PV B-fragments)
__global__ __launch_bounds__(256) void gather_kv(const f16* __restrict__ kc,
                                                 const f16* __restrict__ vc,
                                                 const int* __restrict__ bt,
                                                 f16* __restrict__ kk,
                                                 f16* __restrict__ vvt) {
    int idx = blockIdx.x * 256 + threadIdx.x;      // ((b*S+s)*8+kvh)*128+d, 2^22 total
    int d   = idx & 127;
    int kvh = (idx >> 7) & 7;
    int s   = (idx >> 10) & 2047;
    int b   = idx >> 21;
    int slot = bt[b * 128 + (s >> 4)] * 16 + (s & 15);
    f16 k = kc[((size_t)slot * 8 + kvh) * 128 + d];
    f16 v = vc[((size_t)slot * 8 + kvh) * 128 + d];
    kk [(((size_t)(b * 8 + kvh)) * 2048 + s) * 128 + d] = k;
    vvt[(((size_t)(b * 8 + kvh)) * 128 + d) * 2048 + s] = v;
}

// ---------------------------------------------------------------- flash attention
// grid (qtile=32, h=32, b=2), block 256 (4 waves). Each wave owns 16 q rows.
// K-tile = 64 keys. Online softmax; P round-trips LDS (C-layout -> A-layout).
__global__ __launch_bounds__(256) void attn_fused(const f16* __restrict__ qh,
                                                  const f16* __restrict__ kk,
                                                  const f16* __restrict__ vvt,
                                                  const int* __restrict__ seqlens,
                                                  f16* __restrict__ out) {
    __shared__ f16 Ks[64][136];    // [key][d], +8 pad
    __shared__ f16 Vs[128][72];    // [d][key], +8 pad
    __shared__ f16 Ps[4][16][72];  // per-wave [qrow][key], +8 pad
    const int qt = blockIdx.x, h = blockIdx.y, b = blockIdx.z;
    const int kvh = h >> 2;                       // G = NH/NKV = 4
    const int tid = threadIdx.x, wave = tid >> 6, lane = tid & 63;
    const int quad = lane >> 4, m16 = lane & 15;
    const int qbase = qt * 64;
    const int qw = qbase + wave * 16;

    // Q fragments stay in registers for the whole kernel (HD=128 -> 4 k-chunks)
    const f16* qptr = qh + (((size_t)(b * 32 + h)) * 2048 + qw + m16) * 128;
    f16x8 qf[4];
#pragma unroll
    for (int c = 0; c < 4; ++c) qf[c] = *(const f16x8*)(qptr + c * 32 + quad * 8);

    float m_i[4], l_i[4];
    f32x4 oacc[8];
#pragma unroll
    for (int r = 0; r < 4; ++r) { m_i[r] = NEG_INF; l_i[r] = 0.f; }
#pragma unroll
    for (int dt = 0; dt < 8; ++dt)
#pragma unroll
        for (int e = 0; e < 4; ++e) oacc[dt][e] = 0.f;

    const int seqlen = seqlens[b];
    int kmax = qbase + 64; if (seqlen < kmax) kmax = seqlen;
    const f16* kbp = kk  + ((size_t)(b * 8 + kvh) * 2048) * 128;
    const f16* vbp = vvt + ((size_t)(b * 8 + kvh) * 128) * 2048;

    for (int kt = 0; kt < kmax; kt += 64) {
        __syncthreads();   // protect prior iteration's reads of Ks/Vs
#pragma unroll
        for (int it = 0; it < 4; ++it) {           // K tile: 64 rows x 16 groups
            int g = it * 256 + tid;
            int r_ = g >> 4, c8 = (g & 15) * 8;
            *(f16x8*)&Ks[r_][c8] = *(const f16x8*)(kbp + (size_t)(kt + r_) * 128 + c8);
        }
#pragma unroll
        for (int it = 0; it < 4; ++it) {           // V^T tile: 128 rows x 8 groups
            int g = it * 256 + tid;
            int r_ = g >> 3, c8 = (g & 7) * 8;
            *(f16x8*)&Vs[r_][c8] = *(const f16x8*)(vbp + (size_t)r_ * 2048 + kt + c8);
        }
        __syncthreads();

        // S = Q K^T  (4 n-tiles of 16 keys, contraction over HD in 4 chunks)
        f32x4 sc[4];
#pragma unroll
        for (int nt = 0; nt < 4; ++nt) {
            f32x4 s = {0.f, 0.f, 0.f, 0.f};
#pragma unroll
            for (int c = 0; c < 4; ++c) {
                f16x8 kf = *(const f16x8*)&Ks[nt * 16 + m16][c * 32 + quad * 8];
                s = __builtin_amdgcn_mfma_f32_16x16x32_f16(qf[c], kf, s, 0, 0, 0);
            }
            sc[nt] = s;
        }

        // scale + mask + online softmax (rows = quad*4+r, cols spread over 16 lanes)
        float sv[4][4];
        float mt[4] = {NEG_INF, NEG_INF, NEG_INF, NEG_INF};
#pragma unroll
        for (int nt = 0; nt < 4; ++nt) {
            int kpos = kt + nt * 16 + m16;
#pragma unroll
            for (int r = 0; r < 4; ++r) {
                int qpos = qw + quad * 4 + r;
                float sx = sc[nt][r] * 0.08838834764831845f;
                sx = (kpos <= qpos && kpos < seqlen) ? sx : NEG_INF;
                sv[nt][r] = sx;
                mt[r] = fmaxf(mt[r], sx);
            }
        }
#pragma unroll
        for (int off = 1; off < 16; off <<= 1)
#pragma unroll
            for (int r = 0; r < 4; ++r)
                mt[r] = fmaxf(mt[r], __shfl_xor(mt[r], off, 64));

        float alpha[4], mm[4];
#pragma unroll
        for (int r = 0; r < 4; ++r) {
            float mo = m_i[r];
            float mn = fmaxf(mo, mt[r]);
            float mmr = fmaxf(mn, -1e30f);      // keeps exp() NaN-free when all masked
            alpha[r] = __expf(mo - mmr);
            m_i[r] = mn;
            mm[r] = mmr;
        }
        float rs[4] = {0.f, 0.f, 0.f, 0.f};
#pragma unroll
        for (int nt = 0; nt < 4; ++nt)
#pragma unroll
            for (int r = 0; r < 4; ++r) {
                float pv = __expf(sv[nt][r] - mm[r]);
                rs[r] += pv;
                Ps[wave][quad * 4 + r][nt * 16 + m16] = (f16)pv;
            }
#pragma unroll
        for (int off = 1; off < 16; off <<= 1)
#pragma unroll
            for (int r = 0; r < 4; ++r) rs[r] += __shfl_xor(rs[r], off, 64);
#pragma unroll
        for (int r = 0; r < 4; ++r) l_i[r] = l_i[r] * alpha[r] + rs[r];
#pragma unroll
        for (int dt = 0; dt < 8; ++dt)
#pragma unroll
            for (int r = 0; r < 4; ++r) oacc[dt][r] *= alpha[r];

        __syncthreads();   // Ps visible; Ks/Vs still stable

        // O += P V  (contraction over 64 keys = 2 chunks; 8 d-tiles)
        f16x8 pf[2];
#pragma unroll
        for (int c = 0; c < 2; ++c)
            pf[c] = *(const f16x8*)&Ps[wave][m16][c * 32 + quad * 8];
#pragma unroll
        for (int dt = 0; dt < 8; ++dt)
#pragma unroll
            for (int c = 0; c < 2; ++c) {
                f16x8 vf = *(const f16x8*)&Vs[dt * 16 + m16][c * 32 + quad * 8];
                oacc[dt] = __builtin_amdgcn_mfma_f32_16x16x32_f16(pf[c], vf, oacc[dt], 0, 0, 0);
            }
    }

    // normalize + write [B,S,NH*HD]
#pragma unroll
    for (int r = 0; r < 4; ++r) {
        int qpos = qw + quad * 4 + r;
        float inv = 1.0f / l_i[r];
        f16* op = out + ((size_t)b * 2048 + qpos) * 4096 + h * 128;
#pragma unroll
        for (int dt = 0; dt < 8; ++dt)
            op[dt * 16 + m16] = (f16)(oacc[dt][r] * inv);
    }
}

// ---------------------------------------------------------------- launch
extern "C" void kernel_launch(void* const* d_in, const int* in_sizes, int n_in,
                              void* d_out, int out_size, void* d_ws, size_t ws_size,
                              hipStream_t stream) {
    const float* x     = (const float*)d_in[0];   // [2,2048,4096]
    const float* wqkv  = (const float*)d_in[1];   // [6144,4096]
    const float* wo    = (const float*)d_in[2];   // [4096,4096]
    const float* freqs = (const float*)d_in[3];   // [2048,1,64,2]
    const int*   bt    = (const int*)d_in[6];     // [2,128]
    const int*   seql  = (const int*)d_in[7];     // [2]
    float* out = (float*)d_out;

    char* ws = (char*)d_ws;
    size_t o = 0;
    f16* xh    = (f16*)(ws + o); o += (size_t)4096 * 4096 * 2;   // also reused as attn_h
    f16* wqkvh = (f16*)(ws + o); o += (size_t)6144 * 4096 * 2;
    f16* woh   = (f16*)(ws + o); o += (size_t)4096 * 4096 * 2;
    f16* qkvh  = (f16*)(ws + o); o += (size_t)4096 * 6144 * 2;
    f16* qhp   = (f16*)(ws + o); o += (size_t)4096 * 4096 * 2;
    f16* kc    = (f16*)(ws + o); o += (size_t)4096 * 8 * 128 * 2;
    f16* vc    = (f16*)(ws + o); o += (size_t)4096 * 8 * 128 * 2;
    f16* kkp   = (f16*)(ws + o); o += (size_t)4096 * 8 * 128 * 2;
    f16* vvt   = (f16*)(ws + o); o += (size_t)4096 * 8 * 128 * 2;
    f16* attnh = xh;  // xh dead after GEMM1

    cvt_f32_f16<<<16384, 256, 0, stream>>>(x, xh, 4194304);
    cvt_f32_f16<<<24576, 256, 0, stream>>>(wqkv, wqkvh, 6291456);
    cvt_f32_f16<<<16384, 256, 0, stream>>>(wo, woh, 4194304);

    gemm_bt<f16><<<dim3(48, 32), 256, 0, stream>>>(xh, wqkvh, qkvh, 4096, 6144, 4096);

    rope_scatter<<<49152, 256, 0, stream>>>(qkvh, freqs, bt, qhp, kc, vc);
    gather_kv<<<16384, 256, 0, stream>>>(kc, vc, bt, kkp, vvt);

    attn_fused<<<dim3(32, 32, 2), 256, 0, stream>>>(qhp, kkp, vvt, seql, attnh);

    gemm_bt<float><<<dim3(32, 32), 256, 0, stream>>>(attnh, woh, out, 4096, 4096, 4096);
}

// Round 2
// 1105.871 us; speedup vs baseline: 1.0247x; 1.0247x over previous
//
#include <hip/hip_runtime.h>
#include <hip/hip_fp16.h>

typedef _Float16 f16;
typedef _Float16 f16x4 __attribute__((ext_vector_type(4)));
typedef _Float16 f16x8 __attribute__((ext_vector_type(8)));
typedef float    f32x4 __attribute__((ext_vector_type(4)));

#define NEG_INF (-__builtin_inff())
#define AS1 __attribute__((address_space(1)))
#define AS3 __attribute__((address_space(3)))
// async global->LDS, 16B per lane; LDS dest = wave-uniform base + lane*16
#define GLOAD_LDS16(g, l) \
    __builtin_amdgcn_global_load_lds((AS1 const void*)(g), (AS3 void*)(l), 16, 0, 0)

// ---------------------------------------------------------------- converts
__global__ __launch_bounds__(256) void cvt_f32_f16(const float* __restrict__ in,
                                                   f16* __restrict__ out, int n4) {
    int i = blockIdx.x * 256 + threadIdx.x;
    if (i >= n4) return;
    float4 v = ((const float4*)in)[i];
    f16x4 h = {(f16)v.x, (f16)v.y, (f16)v.z, (f16)v.w};
    ((f16x4*)out)[i] = h;
}

// ---------------------------------------------------------------- GEMM C = A * Bt^T
// A: [M,K] f16, Bt: [N,K] f16, C: [M,N]. 256 thr (4 waves 2x2), tile 128x128, BK=32.
// LDS staged via global_load_lds (16B/lane). Tile stored UNPADDED as 8-half chunks,
// XOR-swizzled by source permutation: chunk (row,c) -> slot row*4 + ((c+(row>>1))&3).
// Fragment ds_read_b128 then lands 2 lanes/bank (free). Store side coalescing intact
// (4 lanes of a row fetch the row's 4 chunks in permuted order, same 64B segment).
template <typename CT>
__global__ __launch_bounds__(256) void gemm_bt(const f16* __restrict__ A,
                                               const f16* __restrict__ Bt,
                                               CT* __restrict__ C, int M, int N, int K) {
    __shared__ f16 As[128 * 32];
    __shared__ f16 Bs[128 * 32];
    const int tid  = threadIdx.x;
    const int wave = tid >> 6, lane = tid & 63;
    const int quad = lane >> 4, m16 = lane & 15;
    const int waveM = (wave >> 1) * 64, waveN = (wave & 1) * 64;
    const int bm = blockIdx.y * 128, bn = blockIdx.x * 128;

    f32x4 acc[4][4];
#pragma unroll
    for (int i = 0; i < 4; ++i)
#pragma unroll
        for (int j = 0; j < 4; ++j)
#pragma unroll
            for (int e = 0; e < 4; ++e) acc[i][j][e] = 0.f;

    // staging: wave w covers chunk slots [w*128, w*128+128), 2 instr of 64 lanes
    const f16* gA[2]; const f16* gB[2]; f16* lA[2]; f16* lB[2];
#pragma unroll
    for (int it = 0; it < 2; ++it) {
        int slot = wave * 128 + it * 64 + lane;
        int row  = slot >> 2;
        int c    = (slot - (row >> 1)) & 3;          // inverse swizzle
        gA[it] = A  + (size_t)(bm + row) * K + c * 8;
        gB[it] = Bt + (size_t)(bn + row) * K + c * 8;
        // LDS base must be wave-uniform: start of this instruction's 64-slot span
        lA[it] = As + (size_t)(wave * 128 + it * 64) * 8;
        lB[it] = Bs + (size_t)(wave * 128 + it * 64) * 8;
    }
    // fragment LDS addresses are k-invariant: chunk (row, quad) at swizzled slot
    const f16* apf[4]; const f16* bpf[4];
#pragma unroll
    for (int t = 0; t < 4; ++t) {
        int rowA = waveM + t * 16 + m16;
        int rowB = waveN + t * 16 + m16;
        apf[t] = As + rowA * 32 + (((quad + (rowA >> 1)) & 3) * 8);
        bpf[t] = Bs + rowB * 32 + (((quad + (rowB >> 1)) & 3) * 8);
    }

    for (int k0 = 0; k0 < K; k0 += 32) {
        __syncthreads();                      // prior ds_reads done before overwrite
#pragma unroll
        for (int it = 0; it < 2; ++it) {
            GLOAD_LDS16(gA[it] + k0, lA[it]);
            GLOAD_LDS16(gB[it] + k0, lB[it]);
        }
        __syncthreads();                      // drains vmcnt(0): staged data visible
        f16x8 af[4], bf[4];
#pragma unroll
        for (int t = 0; t < 4; ++t) af[t] = *(const f16x8*)apf[t];
#pragma unroll
        for (int t = 0; t < 4; ++t) bf[t] = *(const f16x8*)bpf[t];
#pragma unroll
        for (int i = 0; i < 4; ++i)
#pragma unroll
            for (int j = 0; j < 4; ++j)
                acc[i][j] = __builtin_amdgcn_mfma_f32_16x16x32_f16(af[i], bf[j], acc[i][j], 0, 0, 0);
    }

#pragma unroll
    for (int i = 0; i < 4; ++i)
#pragma unroll
        for (int r = 0; r < 4; ++r) {
            int row = bm + waveM + i * 16 + quad * 4 + r;
#pragma unroll
            for (int j = 0; j < 4; ++j) {
                int col = bn + waveN + j * 16 + m16;
                C[(size_t)row * N + col] = (CT)acc[i][j][r];
            }
        }
}

// ---------------------------------------------------------------- RoPE + paged scatter
__global__ __launch_bounds__(256) void rope_scatter(const f16* __restrict__ qkv,
                                                    const float* __restrict__ freqs,
                                                    const int* __restrict__ bt,
                                                    f16* __restrict__ qh,
                                                    f16* __restrict__ kc,
                                                    f16* __restrict__ vc) {
    int idx  = blockIdx.x * 256 + threadIdx.x;     // B*S*3072 pairs
    int row  = idx / 3072;
    int p    = idx - row * 3072;
    int b    = row >> 11, s = row & 2047;
    int head = p >> 6, i = p & 63;
    const f16* src = qkv + (size_t)row * 6144 + head * 128 + 2 * i;
    float v0 = (float)src[0], v1 = (float)src[1];
    if (head < 40) {  // rope on q and k
        float c  = freqs[s * 128 + 2 * i];
        float sn = freqs[s * 128 + 2 * i + 1];
        float r0 = v0 * c - v1 * sn;
        float r1 = v1 * c + v0 * sn;
        v0 = r0; v1 = r1;
    }
    if (head < 32) {
        f16* dst = qh + (((size_t)(b * 32 + head)) * 2048 + s) * 128 + 2 * i;
        dst[0] = (f16)v0; dst[1] = (f16)v1;
    } else {
        int kvh  = head - 32; if (kvh >= 8) kvh -= 8;
        int slot = bt[b * 128 + (s >> 4)] * 16 + (s & 15);
        f16* dst = (head < 40 ? kc : vc) + ((size_t)slot * 8 + kvh) * 128 + 2 * i;
        dst[0] = (f16)v0; dst[1] = (f16)v1;
    }
}

// ---------------------------------------------------------------- gather through block table
__global__ __launch_bounds__(256) void gather_kv(const f16* __restrict__ kc,
                                                 const f16* __restrict__ vc,
                                                 const int* __restrict__ bt,
                                                 f16* __restrict__ kk,
                                                 f16* __restrict__ vvt) {
    int idx = blockIdx.x * 256 + threadIdx.x;
    int d   = idx & 127;
    int kvh = (idx >> 7) & 7;
    int s   = (idx >> 10) & 2047;
    int b   = idx >> 21;
    int slot = bt[b * 128 + (s >> 4)] * 16 + (s & 15);
    f16 k = kc[((size_t)slot * 8 + kvh) * 128 + d];
    f16 v = vc[((size_t)slot * 8 + kvh) * 128 + d];
    kk [(((size_t)(b * 8 + kvh)) * 2048 + s) * 128 + d] = k;
    vvt[(((size_t)(b * 8 + kvh)) * 128 + d) * 2048 + s] = v;
}

// ---------------------------------------------------------------- flash attention
// grid (qtile=32, h=32, b=2), block 256 (4 waves). Wave owns 16 q rows; K-tile 64.
// LDS: Vs [d][key] 18.4 KB + union{Ks, Ps} 17.4 KB = 35.8 KB -> 4 blocks/CU (was 3).
// Ps overlays Ks: safe because the barrier after QK closes all Ks reads, and Ps is
// written+read wave-privately (in-wave lgkmcnt ordering, no extra barrier).
// Heavy tiles first (qt reversed) to shrink the causal-imbalance tail.
__global__ __launch_bounds__(256) void attn_fused(const f16* __restrict__ qh,
                                                  const f16* __restrict__ kk,
                                                  const f16* __restrict__ vvt,
                                                  const int* __restrict__ seqlens,
                                                  f16* __restrict__ out) {
    __shared__ f16 KsPs[64 * 136];   // Ks: [key][d] stride 136; Ps reuses offset 0
    __shared__ f16 Vs[128][72];      // [d][key], +8 pad
    const int qt = 31 - blockIdx.x;  // heavy-first
    const int h = blockIdx.y, b = blockIdx.z;
    const int kvh = h >> 2;                       // G = NH/NKV = 4
    const int tid = threadIdx.x, wave = tid >> 6, lane = tid & 63;
    const int quad = lane >> 4, m16 = lane & 15;
    const int qbase = qt * 64;
    const int qw = qbase + wave * 16;
    f16* Ps = KsPs;                  // [4][16][72] = 4608 halves < 8704

    const f16* qptr = qh + (((size_t)(b * 32 + h)) * 2048 + qw + m16) * 128;
    f16x8 qf[4];
#pragma unroll
    for (int c = 0; c < 4; ++c) qf[c] = *(const f16x8*)(qptr + c * 32 + quad * 8);

    float m_i[4], l_i[4];
    f32x4 oacc[8];
#pragma unroll
    for (int r = 0; r < 4; ++r) { m_i[r] = NEG_INF; l_i[r] = 0.f; }
#pragma unroll
    for (int dt = 0; dt < 8; ++dt)
#pragma unroll
        for (int e = 0; e < 4; ++e) oacc[dt][e] = 0.f;

    const int seqlen = seqlens[b];
    int kmax = qbase + 64; if (seqlen < kmax) kmax = seqlen;
    const f16* kbp = kk  + ((size_t)(b * 8 + kvh) * 2048) * 128;
    const f16* vbp = vvt + ((size_t)(b * 8 + kvh) * 128) * 2048;

    for (int kt = 0; kt < kmax; kt += 64) {
        __syncthreads();   // prior iteration's Ks/Ps/Vs reads complete
#pragma unroll
        for (int it = 0; it < 4; ++it) {           // K tile: 64 rows x 16 groups
            int g = it * 256 + tid;
            int r_ = g >> 4, c8 = (g & 15) * 8;
            *(f16x8*)&KsPs[r_ * 136 + c8] = *(const f16x8*)(kbp + (size_t)(kt + r_) * 128 + c8);
        }
#pragma unroll
        for (int it = 0; it < 4; ++it) {           // V^T tile: 128 rows x 8 groups
            int g = it * 256 + tid;
            int r_ = g >> 3, c8 = (g & 7) * 8;
            *(f16x8*)&Vs[r_][c8] = *(const f16x8*)(vbp + (size_t)r_ * 2048 + kt + c8);
        }
        __syncthreads();

        // S = Q K^T
        f32x4 sc[4];
#pragma unroll
        for (int nt = 0; nt < 4; ++nt) {
            f32x4 s = {0.f, 0.f, 0.f, 0.f};
#pragma unroll
            for (int c = 0; c < 4; ++c) {
                f16x8 kf = *(const f16x8*)&KsPs[(nt * 16 + m16) * 136 + c * 32 + quad * 8];
                s = __builtin_amdgcn_mfma_f32_16x16x32_f16(qf[c], kf, s, 0, 0, 0);
            }
            sc[nt] = s;
        }

        // scale + mask + online softmax (rows = quad*4+r, cols over 16 lanes)
        float sv[4][4];
        float mt[4] = {NEG_INF, NEG_INF, NEG_INF, NEG_INF};
#pragma unroll
        for (int nt = 0; nt < 4; ++nt) {
            int kpos = kt + nt * 16 + m16;
#pragma unroll
            for (int r = 0; r < 4; ++r) {
                int qpos = qw + quad * 4 + r;
                float sx = sc[nt][r] * 0.08838834764831845f;
                sx = (kpos <= qpos && kpos < seqlen) ? sx : NEG_INF;
                sv[nt][r] = sx;
                mt[r] = fmaxf(mt[r], sx);
            }
        }
#pragma unroll
        for (int off = 1; off < 16; off <<= 1)
#pragma unroll
            for (int r = 0; r < 4; ++r)
                mt[r] = fmaxf(mt[r], __shfl_xor(mt[r], off, 64));

        float alpha[4], mm[4];
#pragma unroll
        for (int r = 0; r < 4; ++r) {
            float mo = m_i[r];
            float mn = fmaxf(mo, mt[r]);
            float mmr = fmaxf(mn, -1e30f);      // exp stays NaN-free when all masked
            alpha[r] = __expf(mo - mmr);
            m_i[r] = mn;
            mm[r] = mmr;
        }
        float rs[4] = {0.f, 0.f, 0.f, 0.f};
#pragma unroll
        for (int nt = 0; nt < 4; ++nt)
#pragma unroll
            for (int r = 0; r < 4; ++r) {
                float pv = __expf(sv[nt][r] - mm[r]);
                sv[nt][r] = pv;
                rs[r] += pv;
            }
#pragma unroll
        for (int off = 1; off < 16; off <<= 1)
#pragma unroll
            for (int r = 0; r < 4; ++r) rs[r] += __shfl_xor(rs[r], off, 64);
#pragma unroll
        for (int r = 0; r < 4; ++r) l_i[r] = l_i[r] * alpha[r] + rs[r];
#pragma unroll
        for (int dt = 0; dt < 8; ++dt)
#pragma unroll
            for (int r = 0; r < 4; ++r) oacc[dt][r] *= alpha[r];

        __syncthreads();   // ALL waves done reading Ks before Ps overwrites it

        // P: C-layout regs -> wave-private LDS region -> A-layout fragments
#pragma unroll
        for (int nt = 0; nt < 4; ++nt)
#pragma unroll
            for (int r = 0; r < 4; ++r)
                Ps[(wave * 16 + quad * 4 + r) * 72 + nt * 16 + m16] = (f16)sv[nt][r];

        f16x8 pf[2];
#pragma unroll
        for (int c = 0; c < 2; ++c)
            pf[c] = *(const f16x8*)&Ps[(wave * 16 + m16) * 72 + c * 32 + quad * 8];
#pragma unroll
        for (int dt = 0; dt < 8; ++dt)
#pragma unroll
            for (int c = 0; c < 2; ++c) {
                f16x8 vf = *(const f16x8*)&Vs[dt * 16 + m16][c * 32 + quad * 8];
                oacc[dt] = __builtin_amdgcn_mfma_f32_16x16x32_f16(pf[c], vf, oacc[dt], 0, 0, 0);
            }
    }

    // normalize + write [B,S,NH*HD]
#pragma unroll
    for (int r = 0; r < 4; ++r) {
        int qpos = qw + quad * 4 + r;
        float inv = 1.0f / l_i[r];
        f16* op = out + ((size_t)b * 2048 + qpos) * 4096 + h * 128;
#pragma unroll
        for (int dt = 0; dt < 8; ++dt)
            op[dt * 16 + m16] = (f16)(oacc[dt][r] * inv);
    }
}

// ---------------------------------------------------------------- launch
extern "C" void kernel_launch(void* const* d_in, const int* in_sizes, int n_in,
                              void* d_out, int out_size, void* d_ws, size_t ws_size,
                              hipStream_t stream) {
    const float* x     = (const float*)d_in[0];   // [2,2048,4096]
    const float* wqkv  = (const float*)d_in[1];   // [6144,4096]
    const float* wo    = (const float*)d_in[2];   // [4096,4096]
    const float* freqs = (const float*)d_in[3];   // [2048,1,64,2]
    const int*   bt    = (const int*)d_in[6];     // [2,128]
    const int*   seql  = (const int*)d_in[7];     // [2]
    float* out = (float*)d_out;

    char* ws = (char*)d_ws;
    size_t o = 0;
    f16* xh    = (f16*)(ws + o); o += (size_t)4096 * 4096 * 2;   // reused as attn_h
    f16* wqkvh = (f16*)(ws + o); o += (size_t)6144 * 4096 * 2;
    f16* woh   = (f16*)(ws + o); o += (size_t)4096 * 4096 * 2;
    f16* qkvh  = (f16*)(ws + o); o += (size_t)4096 * 6144 * 2;
    f16* qhp   = (f16*)(ws + o); o += (size_t)4096 * 4096 * 2;
    f16* kc    = (f16*)(ws + o); o += (size_t)4096 * 8 * 128 * 2;
    f16* vc    = (f16*)(ws + o); o += (size_t)4096 * 8 * 128 * 2;
    f16* kkp   = (f16*)(ws + o); o += (size_t)4096 * 8 * 128 * 2;
    f16* vvt   = (f16*)(ws + o); o += (size_t)4096 * 8 * 128 * 2;
    f16* attnh = xh;  // xh dead after GEMM1

    cvt_f32_f16<<<16384, 256, 0, stream>>>(x, xh, 4194304);
    cvt_f32_f16<<<24576, 256, 0, stream>>>(wqkv, wqkvh, 6291456);
    cvt_f32_f16<<<16384, 256, 0, stream>>>(wo, woh, 4194304);

    gemm_bt<f16><<<dim3(48, 32), 256, 0, stream>>>(xh, wqkvh, qkvh, 4096, 6144, 4096);

    rope_scatter<<<49152, 256, 0, stream>>>(qkvh, freqs, bt, qhp, kc, vc);
    gather_kv<<<16384, 256, 0, stream>>>(kc, vc, bt, kkp, vvt);

    attn_fused<<<dim3(32, 32, 2), 256, 0, stream>>>(qhp, kkp, vvt, seql, attnh);

    gemm_bt<float><<<dim3(32, 32), 256, 0, stream>>>(attnh, woh, out, 4096, 4096, 4096);
}